// Round 5
// baseline (162.400 us; speedup 1.0000x reference)
//
#include <hip/hip_runtime.h>
#include <math.h>

constexpr int Bc = 2, Lc = 256, DMc = 256, Hc = 8, DHc = 32;
constexpr float LOG2E = 1.4426950408889634f;
constexpr float NEGC  = -0.72134752044448f;       // -log2e/2
constexpr float RSQRT_DH = 0.17677669529663687f;  // 1/sqrt(32)
#define EXP2 __builtin_amdgcn_exp2f
#define RCP  __builtin_amdgcn_rcpf

// ===========================================================================
// kA: blocks [0,384) = QKV gemm (dispatched first to overlap grel bulk),
//     blocks [384,2560) = g_rel (136 sym tile-pairs x B x H).
// grel per-eval: v_sub, v_mul, v_mul, v_exp, v_fma; mu/w via s_load (wave-
// uniform), -log2e/(2 sg^2) staged in LDS. 4 independent acc chains (k-comp).
// ===========================================================================

template<int R, int PER>
__device__ __forceinline__ void stage_tile(const float* __restrict__ src, int ld,
                                           int row0, int k0, float* __restrict__ dst, int tid) {
    int row = tid / (16 / PER);
    int cb = (tid % (16 / PER)) * PER;
    const float* g = src + (size_t)(row0 + row) * ld + k0 + cb;
    float v[PER];
    #pragma unroll
    for (int u = 0; u < PER; ++u) v[u] = g[u];
    #pragma unroll
    for (int u = 0; u < PER; ++u) dst[(cb + u) * (R + 1) + row] = v[u];
}

__device__ __forceinline__ void gemm32(const float* __restrict__ A, const float* __restrict__ W,
                                       float* __restrict__ C, float sc, int m0, int n0,
                                       float* smem) {
    float* As = smem;
    float* Ws = smem + 16 * 33;
    int tid = threadIdx.x;
    int tx = tid & 15, ty = tid >> 4;
    float acc[2][2] = {};
    for (int k0 = 0; k0 < 256; k0 += 16) {
        stage_tile<32, 2>(A, 256, m0, k0, As, tid);
        stage_tile<32, 2>(W, 256, n0, k0, Ws, tid);
        __syncthreads();
        #pragma unroll
        for (int k = 0; k < 16; ++k) {
            float a0 = As[k * 33 + ty * 2], a1 = As[k * 33 + ty * 2 + 1];
            float w0 = Ws[k * 33 + tx * 2], w1 = Ws[k * 33 + tx * 2 + 1];
            acc[0][0] = fmaf(a0, w0, acc[0][0]);
            acc[0][1] = fmaf(a0, w1, acc[0][1]);
            acc[1][0] = fmaf(a1, w0, acc[1][0]);
            acc[1][1] = fmaf(a1, w1, acc[1][1]);
        }
        __syncthreads();
    }
    #pragma unroll
    for (int u = 0; u < 2; ++u)
        #pragma unroll
        for (int v = 0; v < 2; ++v)
            C[(size_t)(m0 + ty * 2 + u) * DMc + n0 + tx * 2 + v] = acc[u][v] * sc;
}

__global__ void __launch_bounds__(256) kA(
    const float* __restrict__ x, const float* __restrict__ t,
    const float* __restrict__ WQ, const float* __restrict__ WK, const float* __restrict__ WV,
    const float* __restrict__ mu_r, const float* __restrict__ sg_r, const float* __restrict__ w_r,
    float* __restrict__ Qb, float* __restrict__ Kb, float* __restrict__ Vb,
    float* __restrict__ GR)
{
    __shared__ float smem[1088];
    int bx = blockIdx.x;
    int tid = threadIdx.x;
    if (bx < 384) {
        int z = bx >> 7, r = bx & 127;
        int m0 = (r >> 3) * 32, n0 = (r & 7) * 32;
        const float* W = (z == 0) ? WQ : (z == 1) ? WK : WV;
        float* C = (z == 0) ? Qb : (z == 1) ? Kb : Vb;
        gemm32(x, W, C, (z == 0) ? RSQRT_DH : 1.0f, m0, n0, smem);
        return;
    }
    int idx = bx - 384;
    int h = idx & 7, b = (idx >> 3) & 1, p = idx >> 4;
    {   // ns2[512] = -log2e/(2*sigma^2), same layout as inputs (d*16+tg*4+k)
        float2 s2 = *(const float2*)(sg_r + h * 512 + tid * 2);
        float2 o;
        o.x = NEGC / (s2.x * s2.x);
        o.y = NEGC / (s2.y * s2.y);
        *(float2*)(smem + tid * 2) = o;
    }
    __syncthreads();
    int ti = 0;
    for (;; ++ti) { int c = 16 - ti; if (p < c) break; p -= c; }
    int tj = ti + p;
    int di = tid >> 4, dj = tid & 15;
    int i = ti * 16 + di, j = tj * 16 + dj;
    float4 t_i = *(const float4*)(t + (b * Lc + i) * 4);
    float4 t_j = *(const float4*)(t + (b * Lc + j) * 4);
    float tr[4] = {fabsf(t_i.x - t_j.x), fabsf(t_i.y - t_j.y),
                   fabsf(t_i.z - t_j.z), fabsf(t_i.w - t_j.w)};
    float a0 = 0.f, a1 = 0.f, a2 = 0.f, a3 = 0.f;  // independent k-chains
    #pragma unroll
    for (int tg = 0; tg < 4; ++tg) {
        const float* muB = mu_r + h * 512 + tg * 4;
        const float* wB  = w_r  + h * 512 + tg * 4;
        const float* nsB = smem + tg * 4;
        float tv = tr[tg];
        #pragma unroll 4
        for (int d = 0; d < 32; ++d) {
            float4 m4 = *(const float4*)(muB + d * 16);   // s_load
            float4 w4 = *(const float4*)(wB  + d * 16);   // s_load
            float4 n4 = *(const float4*)(nsB + d * 16);   // ds_read_b128
            float d0 = tv - m4.x; a0 = fmaf(w4.x, EXP2(d0 * d0 * n4.x), a0);
            float d1 = tv - m4.y; a1 = fmaf(w4.y, EXP2(d1 * d1 * n4.y), a1);
            float d2 = tv - m4.z; a2 = fmaf(w4.z, EXP2(d2 * d2 * n4.z), a2);
            float d3 = tv - m4.w; a3 = fmaf(w4.w, EXP2(d3 * d3 * n4.w), a3);
        }
    }
    float g = ((a0 + a1) + (a2 + a3)) * (1.0f / 32.0f);
    float* gb = GR + (size_t)(b * Hc + h) * (Lc * Lc);
    gb[i * Lc + j] = g;
    if (ti != tj) {
        float* lt = smem + 544;   // 16x17
        __syncthreads();
        lt[di * 17 + dj] = g;
        __syncthreads();
        gb[(tj * 16 + di) * Lc + (ti * 16 + dj)] = lt[dj * 17 + di];
    }
}

// ===========================================================================
// kFull: per (bh, 16-row i-tile): gabs, S=QK^T, P=XX^T, modulation, softmax,
// PV, and partial out-gemm (AO_h @ WO_h^T) atomically added into out.
// grid (16 it, 16 bh), block 256. out must be pre-zeroed (memset node).
// ===========================================================================
constexpr int O_SQ   = 0;      // 32x17 Q^T
constexpr int O_SXI  = 544;    // 32x17 X_i^T
constexpr int O_SAOT = 1088;   // 32x20 AO^T [d][i]
constexpr int O_SGA  = 1728;   // 16
constexpr int O_SL   = 1760;   // 16x264 logits/probs | overlay: red 16x17, sWOT 32x264
constexpr int O_ST   = 5984;   // 2x32x68 K^T/X^T chunk | overlay: sV 64x36
constexpr int SM_TOT = 10336;

__global__ void __launch_bounds__(256) kFull(
    const float* __restrict__ x, const float* __restrict__ t,
    const float* __restrict__ Q, const float* __restrict__ K, const float* __restrict__ V,
    const float* __restrict__ GR, const float* __restrict__ WO, const float* __restrict__ bO,
    const float* __restrict__ mu_a, const float* __restrict__ sg_a, const float* __restrict__ w_a,
    const float* __restrict__ alpha, const float* __restrict__ beta, const float* __restrict__ gamma,
    float* __restrict__ out)
{
    __shared__ float sm[SM_TOT];
    int it = blockIdx.x, bh = blockIdx.y;
    int b = bh >> 3, h = bh & 7;
    int i0 = it * 16;
    int tid = threadIdx.x;
    int ty = tid >> 4, tx = tid & 15;   // (row i, 16-col group)

    // ---- phase 0: stage Q^T / Xi^T; gabs for the 16 rows -------------------
    {
        int tt = tid & 127;
        int r = tt >> 3;
        int c4 = (tt & 7) * 4;
        const float* src = (tid < 128)
            ? (Q + ((size_t)(b * Lc + i0 + r) * DMc + h * DHc + c4))
            : (x + ((size_t)(b * Lc + i0 + r) * DMc + h * DHc + c4));
        float* dst = (tid < 128) ? (sm + O_SQ) : (sm + O_SXI);
        float4 v = *(const float4*)src;
        dst[(c4 + 0) * 17 + r] = v.x;
        dst[(c4 + 1) * 17 + r] = v.y;
        dst[(c4 + 2) * 17 + r] = v.z;
        dst[(c4 + 3) * 17 + r] = v.w;
    }
    {
        int gi = ty, g = tx;            // row, param-group (32 params each)
        float4 t4 = *(const float4*)(t + (size_t)(b * Lc + i0 + gi) * 4);
        const float* muB = mu_a + h * 512 + g * 32;
        const float* sgB = sg_a + h * 512 + g * 32;
        const float* wB  = w_a  + h * 512 + g * 32;
        float part = 0.f;
        #pragma unroll
        for (int q = 0; q < 8; ++q) {   // tg = q&3 (g*8 % 4 == 0)
            float tv = ((q & 3) == 0) ? t4.x : ((q & 3) == 1) ? t4.y
                     : ((q & 3) == 2) ? t4.z : t4.w;
            float4 m4 = *(const float4*)(muB + q * 4);
            float4 s4 = *(const float4*)(sgB + q * 4);
            float4 w4 = *(const float4*)(wB  + q * 4);
            float d0 = (tv - m4.x) * RCP(s4.x);
            float d1 = (tv - m4.y) * RCP(s4.y);
            float d2 = (tv - m4.z) * RCP(s4.z);
            float d3 = (tv - m4.w) * RCP(s4.w);
            part = fmaf(w4.x, EXP2(d0 * d0 * NEGC), part);
            part = fmaf(w4.y, EXP2(d1 * d1 * NEGC), part);
            part = fmaf(w4.z, EXP2(d2 * d2 * NEGC), part);
            part = fmaf(w4.w, EXP2(d3 * d3 * NEGC), part);
        }
        float* red = sm + O_SL;         // 16x17 overlay
        red[gi * 17 + g] = part;
    }
    __syncthreads();
    if (tid < 16) {
        const float* red = sm + O_SL;
        float s = 0.f;
        #pragma unroll
        for (int j = 0; j < 16; ++j) s += red[tid * 17 + j];
        sm[O_SGA + tid] = s * (1.0f / 32.0f);
    }
    __syncthreads();

    float la = alpha[h], lb = beta[h], lg = gamma[h];
    float ca = 2.0f * la * sm[O_SGA + ty];

    // ---- phase 1: 4 j-chunks of 64: S,P frags + modulation -> sL -----------
    for (int c = 0; c < 4; ++c) {
        int j0 = c * 64;
        {
            int r = tid >> 3;
            int c4 = (tid & 7) * 4;
            #pragma unroll
            for (int uu = 0; uu < 2; ++uu) {
                int rr = r + uu * 32;
                float4 kv = *(const float4*)(K + ((size_t)(b * Lc + j0 + rr) * DMc + h * DHc + c4));
                float4 xv = *(const float4*)(x + ((size_t)(b * Lc + j0 + rr) * DMc + h * DHc + c4));
                float* sKt = sm + O_ST;
                float* sXt = sm + O_ST + 2176;
                sKt[(c4 + 0) * 68 + rr] = kv.x;
                sKt[(c4 + 1) * 68 + rr] = kv.y;
                sKt[(c4 + 2) * 68 + rr] = kv.z;
                sKt[(c4 + 3) * 68 + rr] = kv.w;
                sXt[(c4 + 0) * 68 + rr] = xv.x;
                sXt[(c4 + 1) * 68 + rr] = xv.y;
                sXt[(c4 + 2) * 68 + rr] = xv.z;
                sXt[(c4 + 3) * 68 + rr] = xv.w;
            }
        }
        __syncthreads();
        float accS[4] = {}, accP[4] = {};
        #pragma unroll 4
        for (int k = 0; k < 32; ++k) {
            float qa = sm[O_SQ + k * 17 + ty];
            float xa = sm[O_SXI + k * 17 + ty];
            float4 kb = *(const float4*)(sm + O_ST + k * 68 + tx * 4);
            float4 xb = *(const float4*)(sm + O_ST + 2176 + k * 68 + tx * 4);
            accS[0] = fmaf(qa, kb.x, accS[0]);
            accS[1] = fmaf(qa, kb.y, accS[1]);
            accS[2] = fmaf(qa, kb.z, accS[2]);
            accS[3] = fmaf(qa, kb.w, accS[3]);
            accP[0] = fmaf(xa, xb.x, accP[0]);
            accP[1] = fmaf(xa, xb.y, accP[1]);
            accP[2] = fmaf(xa, xb.z, accP[2]);
            accP[3] = fmaf(xa, xb.w, accP[3]);
        }
        float4 gr = *(const float4*)(GR + (size_t)bh * (Lc * Lc)
                                     + (size_t)(i0 + ty) * Lc + j0 + tx * 4);
        float4 o;
        o.x = accS[0] * fmaf(accP[0], fmaf(lb, gr.x, ca), lg);
        o.y = accS[1] * fmaf(accP[1], fmaf(lb, gr.y, ca), lg);
        o.z = accS[2] * fmaf(accP[2], fmaf(lb, gr.z, ca), lg);
        o.w = accS[3] * fmaf(accP[3], fmaf(lb, gr.w, ca), lg);
        *(float4*)(sm + O_SL + ty * 264 + j0 + tx * 4) = o;
        __syncthreads();
    }

    // ---- phase 2: softmax over sL rows (16-lane shuffles within wave) ------
    float rs;
    {
        float* row = sm + O_SL + ty * 264 + tx * 16;
        float4 p0 = *(const float4*)(row);
        float4 p1 = *(const float4*)(row + 4);
        float4 p2 = *(const float4*)(row + 8);
        float4 p3 = *(const float4*)(row + 12);
        float m = fmaxf(fmaxf(fmaxf(p0.x, p0.y), fmaxf(p0.z, p0.w)),
                        fmaxf(fmaxf(p1.x, p1.y), fmaxf(p1.z, p1.w)));
        m = fmaxf(m, fmaxf(fmaxf(fmaxf(p2.x, p2.y), fmaxf(p2.z, p2.w)),
                           fmaxf(fmaxf(p3.x, p3.y), fmaxf(p3.z, p3.w))));
        #pragma unroll
        for (int s = 1; s < 16; s <<= 1) m = fmaxf(m, __shfl_xor(m, s, 64));
        float4 e0, e1, e2, e3;
        e0.x = EXP2((p0.x - m) * LOG2E); e0.y = EXP2((p0.y - m) * LOG2E);
        e0.z = EXP2((p0.z - m) * LOG2E); e0.w = EXP2((p0.w - m) * LOG2E);
        e1.x = EXP2((p1.x - m) * LOG2E); e1.y = EXP2((p1.y - m) * LOG2E);
        e1.z = EXP2((p1.z - m) * LOG2E); e1.w = EXP2((p1.w - m) * LOG2E);
        e2.x = EXP2((p2.x - m) * LOG2E); e2.y = EXP2((p2.y - m) * LOG2E);
        e2.z = EXP2((p2.z - m) * LOG2E); e2.w = EXP2((p2.w - m) * LOG2E);
        e3.x = EXP2((p3.x - m) * LOG2E); e3.y = EXP2((p3.y - m) * LOG2E);
        e3.z = EXP2((p3.z - m) * LOG2E); e3.w = EXP2((p3.w - m) * LOG2E);
        float sum = ((e0.x + e0.y) + (e0.z + e0.w)) + ((e1.x + e1.y) + (e1.z + e1.w)) +
                    ((e2.x + e2.y) + (e2.z + e2.w)) + ((e3.x + e3.y) + (e3.z + e3.w));
        #pragma unroll
        for (int s = 1; s < 16; s <<= 1) sum += __shfl_xor(sum, s, 64);
        rs = 1.0f / sum;
        __syncthreads();   // all reads done before overwriting with probs
        *(float4*)(row)      = e0;
        *(float4*)(row + 4)  = e1;
        *(float4*)(row + 8)  = e2;
        *(float4*)(row + 12) = e3;
    }
    __syncthreads();

    // ---- phase 3: PV (V streamed per 64-j chunk into sT region) ------------
    float o0 = 0.f, o1 = 0.f;   // thread (ty=i, tx -> d pair 2*tx)
    for (int c = 0; c < 4; ++c) {
        int j0 = c * 64;
        {
            int r = tid >> 3;
            int c4 = (tid & 7) * 4;
            float* sV = sm + O_ST;  // [64][36]
            #pragma unroll
            for (int uu = 0; uu < 2; ++uu) {
                int rr = r + uu * 32;
                *(float4*)(sV + rr * 36 + c4) =
                    *(const float4*)(V + ((size_t)(b * Lc + j0 + rr) * DMc + h * DHc + c4));
            }
        }
        __syncthreads();
        const float* sV = sm + O_ST;
        const float* pr = sm + O_SL + ty * 264 + j0;
        #pragma unroll 4
        for (int j4 = 0; j4 < 64; j4 += 4) {
            float4 p4 = *(const float4*)(pr + j4);
            float2 v0 = *(const float2*)(sV + (j4 + 0) * 36 + tx * 2);
            float2 v1 = *(const float2*)(sV + (j4 + 1) * 36 + tx * 2);
            float2 v2 = *(const float2*)(sV + (j4 + 2) * 36 + tx * 2);
            float2 v3 = *(const float2*)(sV + (j4 + 3) * 36 + tx * 2);
            o0 += p4.x * v0.x + p4.y * v1.x + p4.z * v2.x + p4.w * v3.x;
            o1 += p4.x * v0.y + p4.y * v1.y + p4.z * v2.y + p4.w * v3.y;
        }
        __syncthreads();
    }
    // AO^T [d][i], pitch 20
    sm[O_SAOT + (tx * 2 + 0) * 20 + ty] = o0 * rs;
    sm[O_SAOT + (tx * 2 + 1) * 20 + ty] = o1 * rs;

    // ---- phase 4: partial out = AO_h @ WO_h^T, atomicAdd -------------------
    {   // stage WO^T slice [d][n]: thread n=tid reads WO[n][h*32..+32]
        float* sWOT = sm + O_SL;   // 32 x 264 overlay (sL/sT dead)
        const float* wrow = WO + (size_t)tid * DMc + h * DHc;
        #pragma unroll
        for (int q = 0; q < 8; ++q) {
            float4 w4 = *(const float4*)(wrow + q * 4);
            sWOT[(q * 4 + 0) * 264 + tid] = w4.x;
            sWOT[(q * 4 + 1) * 264 + tid] = w4.y;
            sWOT[(q * 4 + 2) * 264 + tid] = w4.z;
            sWOT[(q * 4 + 3) * 264 + tid] = w4.w;
        }
    }
    __syncthreads();
    {
        int i4 = (tid >> 6) * 4;        // 4 i-rows
        int n4 = (tid & 63) * 4;        // 4 n-cols
        const float* sWOT = sm + O_SL;
        const float* sAOT = sm + O_SAOT;
        float acc[4][4] = {};
        #pragma unroll 8
        for (int d = 0; d < 32; ++d) {
            float4 av = *(const float4*)(sAOT + d * 20 + i4);
            float4 wv = *(const float4*)(sWOT + d * 264 + n4);
            const float* a_ = (const float*)&av;
            const float* w_ = (const float*)&wv;
            #pragma unroll
            for (int u = 0; u < 4; ++u)
                #pragma unroll
                for (int v = 0; v < 4; ++v)
                    acc[u][v] = fmaf(a_[u], w_[v], acc[u][v]);
        }
        #pragma unroll
        for (int u = 0; u < 4; ++u) {
            float* orow = out + (size_t)(b * Lc + i0 + i4 + u) * DMc + n4;
            #pragma unroll
            for (int v = 0; v < 4; ++v) {
                float val = acc[u][v];
                if (h == 0) val += bO[n4 + v];
                atomicAdd(orow + v, val);
            }
        }
    }
}

// ===========================================================================
extern "C" void kernel_launch(void* const* d_in, const int* in_sizes, int n_in,
                              void* d_out, int out_size, void* d_ws, size_t ws_size,
                              hipStream_t stream) {
    (void)in_sizes; (void)n_in; (void)ws_size;
    const float* x      = (const float*)d_in[0];
    const float* t      = (const float*)d_in[1];
    const float* WQ     = (const float*)d_in[2];
    const float* WK     = (const float*)d_in[3];
    const float* WV     = (const float*)d_in[4];
    const float* WO     = (const float*)d_in[5];
    const float* bO     = (const float*)d_in[6];
    const float* mu_abs = (const float*)d_in[7];
    const float* sg_abs = (const float*)d_in[8];
    const float* w_abs  = (const float*)d_in[9];
    const float* mu_rel = (const float*)d_in[10];
    const float* sg_rel = (const float*)d_in[11];
    const float* w_rel  = (const float*)d_in[12];
    const float* alpha  = (const float*)d_in[13];
    const float* beta   = (const float*)d_in[14];
    const float* gamma  = (const float*)d_in[15];
    float* out = (float*)d_out;
    float* ws = (float*)d_ws;

    float* Qb = ws;                // 131072 floats
    float* Kb = ws + 131072;
    float* Vb = ws + 262144;
    float* GR = ws + 393216;       // 1048576 (g_rel)

    hipMemsetAsync(out, 0, (size_t)out_size * sizeof(float), stream);
    kA<<<dim3(2560), dim3(256), 0, stream>>>(x, t, WQ, WK, WV,
                                             mu_rel, sg_rel, w_rel,
                                             Qb, Kb, Vb, GR);
    kFull<<<dim3(16, 16), dim3(256), 0, stream>>>(x, t, Qb, Kb, Vb, GR, WO, bO,
                                                  mu_abs, sg_abs, w_abs,
                                                  alpha, beta, gamma, out);
}